// Round 21
// baseline (167.253 us; speedup 1.0000x reference)
//
#include <hip/hip_runtime.h>
#include <hip/hip_bf16.h>

typedef __attribute__((ext_vector_type(8))) __bf16 bf16x8;
typedef __attribute__((ext_vector_type(4))) __bf16 bf16x4;
typedef __attribute__((ext_vector_type(4))) float f32x4;

#define E_ 768
#define HEADS 12
#define HD 64
#define S_ 2048
#define B_ 4

__device__ inline unsigned short f2bf(float f) {
    union { float f; unsigned int u; } x{f};
    unsigned int r = x.u + 0x7FFFu + ((x.u >> 16) & 1u);
    return (unsigned short)(r >> 16);
}

__device__ inline float fexp2(float x) { return __builtin_amdgcn_exp2f(x); }

// ---------- transpose + convert: w[K][N] fp32 -> wT[N][K] bf16 ----------
__global__ void transpose_cvt(const float* __restrict__ w, unsigned short* __restrict__ wT,
                              int K, int N) {
    __shared__ float tile[32][33];
    int n0 = blockIdx.x * 32, k0 = blockIdx.y * 32;
    int tx = threadIdx.x, ty = threadIdx.y;
    tile[ty][tx] = w[(size_t)(k0 + ty) * N + n0 + tx];
    __syncthreads();
    wT[(size_t)(n0 + ty) * K + k0 + tx] = f2bf(tile[tx][ty]);
}

// ---------- bf16 MFMA GEMM, m97 structure, BN=64, XCD-chunked swizzle ----------
// MODE 0: qkv, A = fp32 x fused-converted during reg-staging (cvt kernel
//         eliminated; (__bf16) cast = RNE = f2bf, bit-identical). T14 split:
//         next A-tile loads issued after the stage barrier. Q pre-scaled by
//         0.125*log2e. Outputs restaged in LDS for coalesced stores.
// MODE 1: bf16 A via global_load_lds; fp32 out + bias.
template<int MODE>
__global__ __launch_bounds__(256) void gemm16(
    const float* __restrict__ Af,
    const unsigned short* __restrict__ A, const unsigned short* __restrict__ Bt,
    const float* __restrict__ bias,
    unsigned short* __restrict__ Qo, unsigned short* __restrict__ Ko,
    unsigned short* __restrict__ Vt, float* __restrict__ Of,
    int M, int N, int K)
{
    constexpr int BN = 64;
    constexpr int NJ = 2;
    __shared__ unsigned short Sh[128 * 64 + 64 * 64];   // A-tile + B-tile = 24 KB
    unsigned short* Ash = Sh;
    unsigned short* Bsh = Sh + 128 * 64;

    const int nbx = N / BN;
    const int nwg = (M >> 7) * nbx;
    const int cpx = nwg >> 3;
    const int orig = blockIdx.x;
    const int wgid = (orig & 7) * cpx + (orig >> 3);   // XCD-chunked (nwg%8==0)
    const int row0 = (wgid / nbx) * 128;
    const int col0 = (wgid % nbx) * BN;

    const int t = threadIdx.x;
    const int w = t >> 6, lane = t & 63;
    const int lr = lane & 15, lc = lane >> 4;
    const int wrow = (w >> 1) * 64;
    const int wcol = (w & 1) * 32;

    const int srow = lane >> 3;
    const int sslot = lane & 7;

    f32x4 acc[4][NJ] = {};

    float4 ar0[4], ar1[4];
    if constexpr (MODE == 0) {
        // prologue: A-regs for k0 = 0
#pragma unroll
        for (int j = 0; j < 4; j++) {
            const float* gx = Af + (size_t)(row0 + j * 32 + w * 8 + srow) * K + sslot * 8;
            ar0[j] = *reinterpret_cast<const float4*>(gx);
            ar1[j] = *reinterpret_cast<const float4*>(gx + 4);
        }
    }

    for (int k0 = 0; k0 < K; k0 += 64) {
        if constexpr (MODE == 0) {
            // convert + LDS-write current A-tile from regs
#pragma unroll
            for (int j = 0; j < 4; j++) {
                const int rbase = j * 32 + w * 8;
                bf16x8 pk;
                pk[0] = (__bf16)ar0[j].x; pk[1] = (__bf16)ar0[j].y;
                pk[2] = (__bf16)ar0[j].z; pk[3] = (__bf16)ar0[j].w;
                pk[4] = (__bf16)ar1[j].x; pk[5] = (__bf16)ar1[j].y;
                pk[6] = (__bf16)ar1[j].z; pk[7] = (__bf16)ar1[j].w;
                *reinterpret_cast<bf16x8*>(&Ash[(rbase + srow) * 64 + sslot * 8]) = pk;
            }
        } else {
#pragma unroll
            for (int j = 0; j < 4; j++) {
                const int rbase = j * 32 + w * 8;
                const unsigned short* ga = A + (size_t)(row0 + rbase + srow) * K + k0 + sslot * 8;
                __builtin_amdgcn_global_load_lds(
                    (const __attribute__((address_space(1))) void*)ga,
                    (__attribute__((address_space(3))) void*)&Ash[rbase * 64], 16, 0, 0);
            }
        }
#pragma unroll
        for (int j = 0; j < NJ; j++) {
            const int rbase = j * 32 + w * 8;
            const unsigned short* gb = Bt + (size_t)(col0 + rbase + srow) * K + k0 + sslot * 8;
            __builtin_amdgcn_global_load_lds(
                (const __attribute__((address_space(1))) void*)gb,
                (__attribute__((address_space(3))) void*)&Bsh[rbase * 64], 16, 0, 0);
        }
        __syncthreads();

        if constexpr (MODE == 0) {
            // T14: issue next A-tile loads; they land under the MFMA compute
            if (k0 + 64 < K) {
#pragma unroll
                for (int j = 0; j < 4; j++) {
                    const float* gx = Af + (size_t)(row0 + j * 32 + w * 8 + srow) * K + (k0 + 64) + sslot * 8;
                    ar0[j] = *reinterpret_cast<const float4*>(gx);
                    ar1[j] = *reinterpret_cast<const float4*>(gx + 4);
                }
            }
        }

#pragma unroll
        for (int ks = 0; ks < 2; ks++) {
            bf16x8 a[4], b[NJ];
#pragma unroll
            for (int i = 0; i < 4; i++)
                a[i] = *reinterpret_cast<const bf16x8*>(&Ash[(wrow + i * 16 + lr) * 64 + ks * 32 + lc * 8]);
#pragma unroll
            for (int j2 = 0; j2 < NJ; j2++)
                b[j2] = *reinterpret_cast<const bf16x8*>(&Bsh[(wcol + j2 * 16 + lr) * 64 + ks * 32 + lc * 8]);
#pragma unroll
            for (int i = 0; i < 4; i++)
#pragma unroll
                for (int j2 = 0; j2 < NJ; j2++)
                    acc[i][j2] = __builtin_amdgcn_mfma_f32_16x16x32_bf16(a[i], b[j2], acc[i][j2], 0, 0, 0);
        }
        __syncthreads();
    }

    if constexpr (MODE == 0) {
        const int bb = row0 >> 11;
        const int s0 = row0 & (S_ - 1);
        const int which = col0 / E_;                   // 0=Q, 1=K, 2=V (uniform per block)
        const int h = (col0 - which * E_) >> 6;        // single head per block
        const size_t bh = (size_t)(bb * HEADS + h);
        if (which == 2) {
            // ---- V: transpose-restage -> 256B stores along s ----
#pragma unroll
            for (int i = 0; i < 4; i++)
#pragma unroll
                for (int j = 0; j < NJ; j++) {
                    const int c = wcol + j * 16 + lr;
                    const float bv = bias[col0 + c];
#pragma unroll
                    for (int r = 0; r < 4; r++) {
                        const int row = wrow + i * 16 + lc * 4 + r;
                        Sh[c * 128 + (row ^ ((c & 15) << 3))] = f2bf(acc[i][j][r] + bv);
                    }
                }
            __syncthreads();
#pragma unroll
            for (int pass = 0; pass < 4; pass++) {
                const int c = pass * 16 + (t >> 4);    // 0..63 (= d)
                const int sL = (t & 15) * 8;           // 0..120
                bf16x8 vv = *reinterpret_cast<const bf16x8*>(&Sh[c * 128 + (sL ^ ((c & 15) << 3))]);
                *reinterpret_cast<bf16x8*>(&Vt[(bh * HD + c) * S_ + s0 + sL]) = vv;
            }
            return;
        }
        // ---- Q/K: row-major restage -> 128B stores along d ----
        const float qsc = (which == 0) ? 0.18033688f : 1.0f;   // 0.125*log2e into Q
        unsigned short* dst = (which == 0) ? Qo : Ko;
#pragma unroll
        for (int i = 0; i < 4; i++)
#pragma unroll
            for (int j = 0; j < NJ; j++) {
                const int c = wcol + j * 16 + lr;
                const float bv = bias[col0 + c];
#pragma unroll
                for (int r = 0; r < 4; r++) {
                    const int row = wrow + i * 16 + lc * 4 + r;
                    Sh[row * 64 + (c ^ ((row & 7) << 3))] = f2bf((acc[i][j][r] + bv) * qsc);
                }
            }
        __syncthreads();
#pragma unroll
        for (int pass = 0; pass < 4; pass++) {
            const int row = pass * 32 + (t >> 3);      // 0..127 (s offset)
            const int c2 = (t & 7) * 8;                // 0..56 (= d base)
            bf16x8 vv = *reinterpret_cast<const bf16x8*>(&Sh[row * 64 + (c2 ^ ((row & 7) << 3))]);
            *reinterpret_cast<bf16x8*>(&dst[(bh * S_ + s0 + row) * HD + c2]) = vv;
        }
    } else {
#pragma unroll
        for (int i = 0; i < 4; i++)
#pragma unroll
            for (int j = 0; j < NJ; j++) {
                int col = col0 + wcol + j * 16 + lr;
                float bv = bias[col];
#pragma unroll
                for (int r = 0; r < 4; r++) {
                    int row = row0 + wrow + i * 16 + lc * 4 + r;
                    Of[(size_t)row * N + col] = acc[i][j][r] + bv;
                }
            }
    }
}

// ---------- causal flash attention, one q-tile per block ----------
// grid 1536; heavy/light INTERLEAVED mapping: u=g/48, tile = (u&1)? u>>1
// : 31-(u>>1) -> dispatch alternates 31,0,30,1,... so each CU's batch mixes
// block sizes (smooth drain). Inner loop identical to R19/R20 (verified).
__global__ __launch_bounds__(256) void attn_kernel(
    const unsigned short* __restrict__ Q, const unsigned short* __restrict__ Kd,
    const unsigned short* __restrict__ Vt, unsigned short* __restrict__ O)
{
    __shared__ unsigned short Ksh[128 * 64];
    __shared__ unsigned short Vsh[64 * 128];

    const int t = threadIdx.x;
    const int w = t >> 6, lane = t & 63;
    const int lr = lane & 15, lc = lane >> 4;
    const int g = blockIdx.x;
    const int u = g / 48;
    const int tile = (u & 1) ? (u >> 1) : (31 - (u >> 1));
    const int bh = g % 48;
    const int qrow0 = tile * 64 + w * 16;
    const int nIter = (tile + 2) >> 1;

    const unsigned short* Qb = Q + (size_t)bh * S_ * HD;
    const unsigned short* Kb = Kd + (size_t)bh * S_ * HD;
    const unsigned short* Vb = Vt + (size_t)bh * HD * S_;

    const int srK = t >> 3, ssK = t & 7;
    const int kws = ((ssK ^ (srK & 7)) << 3);
    const int srV = t >> 4, ssV = t & 15;
    const int vs1 = (ssV >> 2) * 4 + (ssV & 1) * 2;
    const int voff = ((ssV >> 1) & 1) * 4;
    const int vws1 = ((vs1 ^ srV) << 3) + voff;
    const int vws2 = (((vs1 + 1) ^ srV) << 3) + voff;
    const int r7 = lr & 7;

    const unsigned short* KbS = Kb + (size_t)srK * HD + ssK * 8;
    const unsigned short* VbS = Vb + (size_t)srV * S_ + ssV * 8;

    bf16x8 aq0, aq1;
    aq0 = *reinterpret_cast<const bf16x8*>(Qb + (size_t)(qrow0 + lr) * HD + lc * 8);
    aq1 = *reinterpret_cast<const bf16x8*>(Qb + (size_t)(qrow0 + lr) * HD + 32 + lc * 8);

    f32x4 o[4] = {};
    float m = -INFINITY, l = 0.f;
    const int bb = bh / HEADS, hh = bh - bb * HEADS;
    const int qrow = qrow0 + lr;

    bf16x8 kreg[4], vreg[4];
#pragma unroll
    for (int i = 0; i < 4; i++) {
        kreg[i] = *reinterpret_cast<const bf16x8*>(KbS + i * 32 * HD);
        vreg[i] = *reinterpret_cast<const bf16x8*>(VbS + i * 16 * S_);
    }

    for (int it = 0; it < nIter; ++it) {
        __syncthreads();
#pragma unroll
        for (int i = 0; i < 4; i++) {
            *reinterpret_cast<bf16x8*>(&Ksh[(srK + i * 32) * 64 + kws]) = kreg[i];
            union { bf16x8 v; bf16x4 h[2]; } u2;
            u2.v = vreg[i];
            const int vrow = (srV + i * 16) * 128;
            *reinterpret_cast<bf16x4*>(&Vsh[vrow + vws1]) = u2.h[0];
            *reinterpret_cast<bf16x4*>(&Vsh[vrow + vws2]) = u2.h[1];
        }
        __syncthreads();

        if (it + 1 < nIter) {
            const int nkv0 = (it + 1) * 128;
#pragma unroll
            for (int i = 0; i < 4; i++) {
                kreg[i] = *reinterpret_cast<const bf16x8*>(KbS + (size_t)nkv0 * HD + i * 32 * HD);
                vreg[i] = *reinterpret_cast<const bf16x8*>(VbS + nkv0 + i * 16 * S_);
            }
        }

        const int kv0 = it * 128;
        const bool needMask = (it == nIter - 1);

        float p[8][4];
#pragma unroll
        for (int kt = 0; kt < 8; kt++) {
            const int row = kt * 16 + lr;
            const bf16x8 bk0 = *reinterpret_cast<const bf16x8*>(&Ksh[row * 64 + ((lc ^ r7) << 3)]);
            const bf16x8 bk1 = *reinterpret_cast<const bf16x8*>(&Ksh[row * 64 + (((4 + lc) ^ r7) << 3)]);
            f32x4 s = {};
            s = __builtin_amdgcn_mfma_f32_16x16x32_bf16(bk0, aq0, s, 0, 0, 0);
            s = __builtin_amdgcn_mfma_f32_16x16x32_bf16(bk1, aq1, s, 0, 0, 0);
#pragma unroll
            for (int r = 0; r < 4; r++) p[kt][r] = s[r];
        }
        if (needMask) {
#pragma unroll
            for (int kt = 0; kt < 8; kt++) {
                const int kbase = kv0 + kt * 16 + lc * 4;
#pragma unroll
                for (int r = 0; r < 4; r++)
                    if (kbase + r > qrow) p[kt][r] = -1e30f;
            }
        }

        float rm = -1e30f;
#pragma unroll
        for (int kt = 0; kt < 8; kt++)
#pragma unroll
            for (int r = 0; r < 4; r++) rm = fmaxf(rm, p[kt][r]);
        rm = fmaxf(rm, __shfl_xor(rm, 16));
        rm = fmaxf(rm, __shfl_xor(rm, 32));

        const bool grow = !__all(rm <= m);
        float mn = m, sc;
        if (grow) {
            mn = fmaxf(m, rm);
            sc = fexp2(m - mn);
        }

        float rs = 0.f;
#pragma unroll
        for (int kt = 0; kt < 8; kt++)
#pragma unroll
            for (int r = 0; r < 4; r++) {
                float e = fexp2(p[kt][r] - mn);
                p[kt][r] = e; rs += e;
            }
        rs += __shfl_xor(rs, 16);
        rs += __shfl_xor(rs, 32);

        if (grow) {
            l = l * sc + rs;
            m = mn;
            float scq[4];
#pragma unroll
            for (int r = 0; r < 4; r++) scq[r] = __shfl(sc, lc * 4 + r);
#pragma unroll
            for (int dt = 0; dt < 4; dt++)
#pragma unroll
                for (int r = 0; r < 4; r++) o[dt][r] *= scq[r];
        } else {
            l += rs;
        }

        bf16x8 ap[4];
#pragma unroll
        for (int kc = 0; kc < 4; kc++) {
            union { bf16x8 v; __bf16 b[8]; } u2;
            u2.b[0] = (__bf16)p[2 * kc][0];     u2.b[1] = (__bf16)p[2 * kc][1];
            u2.b[2] = (__bf16)p[2 * kc][2];     u2.b[3] = (__bf16)p[2 * kc][3];
            u2.b[4] = (__bf16)p[2 * kc + 1][0]; u2.b[5] = (__bf16)p[2 * kc + 1][1];
            u2.b[6] = (__bf16)p[2 * kc + 1][2]; u2.b[7] = (__bf16)p[2 * kc + 1][3];
            ap[kc] = u2.v;
        }

#pragma unroll
        for (int dt = 0; dt < 4; dt++) {
            const int row = dt * 16 + lr;
#pragma unroll
            for (int kc = 0; kc < 4; kc++) {
                const bf16x8 bv = *reinterpret_cast<const bf16x8*>(
                    &Vsh[row * 128 + (((kc * 4 + lc) ^ lr) << 3)]);
                o[dt] = __builtin_amdgcn_mfma_f32_16x16x32_bf16(ap[kc], bv, o[dt], 0, 0, 0);
            }
        }
    }

    {
        float lq[4];
#pragma unroll
        for (int r = 0; r < 4; r++) lq[r] = __shfl(l, lc * 4 + r);
#pragma unroll
        for (int r = 0; r < 4; r++) {
            float inv = 1.f / lq[r];
            int qr = qrow0 + lc * 4 + r;
#pragma unroll
            for (int dt = 0; dt < 4; dt++)
                O[((size_t)(bb * S_ + qr)) * E_ + hh * HD + dt * 16 + lr] = f2bf(o[dt][r] * inv);
        }
    }
}

extern "C" void kernel_launch(void* const* d_in, const int* in_sizes, int n_in,
                              void* d_out, int out_size, void* d_ws, size_t ws_size,
                              hipStream_t stream) {
    const float* x      = (const float*)d_in[0];
    const float* w_attn = (const float*)d_in[1];
    const float* b_attn = (const float*)d_in[2];
    const float* w_proj = (const float*)d_in[3];
    const float* b_proj = (const float*)d_in[4];
    float* out = (float*)d_out;

    char* ws = (char*)d_ws;
    const size_t M = (size_t)B_ * S_;             // 8192
    unsigned short* waT = (unsigned short*)(ws + 12582912);              // 2304*768
    unsigned short* wpT = (unsigned short*)(ws + 16121856);              // 768*768
    unsigned short* Qb  = (unsigned short*)(ws + 17301504);              // BH*S*D
    unsigned short* Kb  = (unsigned short*)(ws + 29884416);
    unsigned short* Vt  = (unsigned short*)(ws + 42467328);
    unsigned short* AO  = (unsigned short*)(ws + 55050240);              // 8192*768

    transpose_cvt<<<dim3(3 * E_ / 32, E_ / 32), dim3(32, 32), 0, stream>>>(w_attn, waT, E_, 3 * E_);
    transpose_cvt<<<dim3(E_ / 32, E_ / 32), dim3(32, 32), 0, stream>>>(w_proj, wpT, E_, E_);

    gemm16<0><<<2304, 256, 0, stream>>>(
        x, nullptr, waT, b_attn, Qb, Kb, Vt, nullptr, (int)M, 3 * E_, E_);

    attn_kernel<<<1536, 256, 0, stream>>>(Qb, Kb, Vt, AO);

    gemm16<1><<<768, 256, 0, stream>>>(
        nullptr, AO, wpT, b_proj, nullptr, nullptr, nullptr, out, (int)M, E_, E_);
}

// Round 22
// 159.313 us; speedup vs baseline: 1.0498x; 1.0498x over previous
//
#include <hip/hip_runtime.h>
#include <hip/hip_bf16.h>

typedef __attribute__((ext_vector_type(8))) __bf16 bf16x8;
typedef __attribute__((ext_vector_type(4))) __bf16 bf16x4;
typedef __attribute__((ext_vector_type(4))) float f32x4;

#define E_ 768
#define HEADS 12
#define HD 64
#define S_ 2048
#define B_ 4

__device__ inline unsigned short f2bf(float f) {
    union { float f; unsigned int u; } x{f};
    unsigned int r = x.u + 0x7FFFu + ((x.u >> 16) & 1u);
    return (unsigned short)(r >> 16);
}

__device__ inline float fexp2(float x) { return __builtin_amdgcn_exp2f(x); }

// ---------- fp32 -> bf16 elementwise (x) ----------
__global__ void cvt_kernel(const float* __restrict__ in, unsigned short* __restrict__ out, int n4) {
    int i = blockIdx.x * blockDim.x + threadIdx.x;
    if (i < n4) {
        float4 v = reinterpret_cast<const float4*>(in)[i];
        ushort4 o;
        o.x = f2bf(v.x); o.y = f2bf(v.y); o.z = f2bf(v.z); o.w = f2bf(v.w);
        reinterpret_cast<ushort4*>(out)[i] = o;
    }
}

// ---------- transpose + convert: w[K][N] fp32 -> wT[N][K] bf16 ----------
__global__ void transpose_cvt(const float* __restrict__ w, unsigned short* __restrict__ wT,
                              int K, int N) {
    __shared__ float tile[32][33];
    int n0 = blockIdx.x * 32, k0 = blockIdx.y * 32;
    int tx = threadIdx.x, ty = threadIdx.y;
    tile[ty][tx] = w[(size_t)(k0 + ty) * N + n0 + tx];
    __syncthreads();
    wT[(size_t)(n0 + ty) * K + k0 + tx] = f2bf(tile[tx][ty]);
}

// ---------- bf16 MFMA GEMM, m97 structure, BN=64, XCD-chunked swizzle ----------
// (R20's verified version: bf16 A via global_load_lds in both modes)
// MODE 0: qkv. Q pre-scaled by 0.125*log2e. Outputs restaged in LDS for
//         coalesced stores (V transposed along s; Q/K row-major along d).
// MODE 1: fp32 out + bias.
template<int MODE>
__global__ __launch_bounds__(256) void gemm16(
    const unsigned short* __restrict__ A, const unsigned short* __restrict__ Bt,
    const float* __restrict__ bias,
    unsigned short* __restrict__ Qo, unsigned short* __restrict__ Ko,
    unsigned short* __restrict__ Vt, float* __restrict__ Of,
    int M, int N, int K)
{
    constexpr int BN = 64;
    constexpr int NJ = 2;
    __shared__ unsigned short Sh[128 * 64 + 64 * 64];   // A-tile + B-tile = 24 KB
    unsigned short* Ash = Sh;
    unsigned short* Bsh = Sh + 128 * 64;

    const int nbx = N / BN;
    const int nwg = (M >> 7) * nbx;
    const int cpx = nwg >> 3;
    const int orig = blockIdx.x;
    const int wgid = (orig & 7) * cpx + (orig >> 3);   // XCD-chunked (nwg%8==0)
    const int row0 = (wgid / nbx) * 128;
    const int col0 = (wgid % nbx) * BN;

    const int t = threadIdx.x;
    const int w = t >> 6, lane = t & 63;
    const int lr = lane & 15, lc = lane >> 4;
    const int wrow = (w >> 1) * 64;
    const int wcol = (w & 1) * 32;

    const int srow = lane >> 3;
    const int sslot = lane & 7;

    f32x4 acc[4][NJ] = {};

    for (int k0 = 0; k0 < K; k0 += 64) {
#pragma unroll
        for (int j = 0; j < 4; j++) {
            const int rbase = j * 32 + w * 8;
            const unsigned short* ga = A + (size_t)(row0 + rbase + srow) * K + k0 + sslot * 8;
            __builtin_amdgcn_global_load_lds(
                (const __attribute__((address_space(1))) void*)ga,
                (__attribute__((address_space(3))) void*)&Ash[rbase * 64], 16, 0, 0);
        }
#pragma unroll
        for (int j = 0; j < NJ; j++) {
            const int rbase = j * 32 + w * 8;
            const unsigned short* gb = Bt + (size_t)(col0 + rbase + srow) * K + k0 + sslot * 8;
            __builtin_amdgcn_global_load_lds(
                (const __attribute__((address_space(1))) void*)gb,
                (__attribute__((address_space(3))) void*)&Bsh[rbase * 64], 16, 0, 0);
        }
        __syncthreads();

#pragma unroll
        for (int ks = 0; ks < 2; ks++) {
            bf16x8 a[4], b[NJ];
#pragma unroll
            for (int i = 0; i < 4; i++)
                a[i] = *reinterpret_cast<const bf16x8*>(&Ash[(wrow + i * 16 + lr) * 64 + ks * 32 + lc * 8]);
#pragma unroll
            for (int j2 = 0; j2 < NJ; j2++)
                b[j2] = *reinterpret_cast<const bf16x8*>(&Bsh[(wcol + j2 * 16 + lr) * 64 + ks * 32 + lc * 8]);
#pragma unroll
            for (int i = 0; i < 4; i++)
#pragma unroll
                for (int j2 = 0; j2 < NJ; j2++)
                    acc[i][j2] = __builtin_amdgcn_mfma_f32_16x16x32_bf16(a[i], b[j2], acc[i][j2], 0, 0, 0);
        }
        __syncthreads();
    }

    if constexpr (MODE == 0) {
        const int bb = row0 >> 11;
        const int s0 = row0 & (S_ - 1);
        const int which = col0 / E_;                   // 0=Q, 1=K, 2=V (uniform per block)
        const int h = (col0 - which * E_) >> 6;        // single head per block
        const size_t bh = (size_t)(bb * HEADS + h);
        if (which == 2) {
            // ---- V: transpose-restage -> 256B stores along s ----
#pragma unroll
            for (int i = 0; i < 4; i++)
#pragma unroll
                for (int j = 0; j < NJ; j++) {
                    const int c = wcol + j * 16 + lr;
                    const float bv = bias[col0 + c];
#pragma unroll
                    for (int r = 0; r < 4; r++) {
                        const int row = wrow + i * 16 + lc * 4 + r;
                        Sh[c * 128 + (row ^ ((c & 15) << 3))] = f2bf(acc[i][j][r] + bv);
                    }
                }
            __syncthreads();
#pragma unroll
            for (int pass = 0; pass < 4; pass++) {
                const int c = pass * 16 + (t >> 4);    // 0..63 (= d)
                const int sL = (t & 15) * 8;           // 0..120
                bf16x8 vv = *reinterpret_cast<const bf16x8*>(&Sh[c * 128 + (sL ^ ((c & 15) << 3))]);
                *reinterpret_cast<bf16x8*>(&Vt[(bh * HD + c) * S_ + s0 + sL]) = vv;
            }
            return;
        }
        // ---- Q/K: row-major restage -> 128B stores along d ----
        const float qsc = (which == 0) ? 0.18033688f : 1.0f;   // 0.125*log2e into Q
        unsigned short* dst = (which == 0) ? Qo : Ko;
#pragma unroll
        for (int i = 0; i < 4; i++)
#pragma unroll
            for (int j = 0; j < NJ; j++) {
                const int c = wcol + j * 16 + lr;
                const float bv = bias[col0 + c];
#pragma unroll
                for (int r = 0; r < 4; r++) {
                    const int row = wrow + i * 16 + lc * 4 + r;
                    Sh[row * 64 + (c ^ ((row & 7) << 3))] = f2bf((acc[i][j][r] + bv) * qsc);
                }
            }
        __syncthreads();
#pragma unroll
        for (int pass = 0; pass < 4; pass++) {
            const int row = pass * 32 + (t >> 3);      // 0..127 (s offset)
            const int c2 = (t & 7) * 8;                // 0..56 (= d base)
            bf16x8 vv = *reinterpret_cast<const bf16x8*>(&Sh[row * 64 + (c2 ^ ((row & 7) << 3))]);
            *reinterpret_cast<bf16x8*>(&dst[(bh * S_ + s0 + row) * HD + c2]) = vv;
        }
    } else {
#pragma unroll
        for (int i = 0; i < 4; i++)
#pragma unroll
            for (int j = 0; j < NJ; j++) {
                int col = col0 + wcol + j * 16 + lr;
                float bv = bias[col];
#pragma unroll
                for (int r = 0; r < 4; r++) {
                    int row = row0 + wrow + i * 16 + lc * 4 + r;
                    Of[(size_t)row * N + col] = acc[i][j][r] + bv;
                }
            }
    }
}

// ---------- causal flash attention, one q-tile per block ----------
// grid 1536; heavy/light INTERLEAVED mapping (tested in isolation this
// round): u=g/48, tile = (u&1)? u>>1 : 31-(u>>1). Inner loop identical to
// R19/R20 (verified).
__global__ __launch_bounds__(256) void attn_kernel(
    const unsigned short* __restrict__ Q, const unsigned short* __restrict__ Kd,
    const unsigned short* __restrict__ Vt, unsigned short* __restrict__ O)
{
    __shared__ unsigned short Ksh[128 * 64];
    __shared__ unsigned short Vsh[64 * 128];

    const int t = threadIdx.x;
    const int w = t >> 6, lane = t & 63;
    const int lr = lane & 15, lc = lane >> 4;
    const int g = blockIdx.x;
    const int u = g / 48;
    const int tile = (u & 1) ? (u >> 1) : (31 - (u >> 1));
    const int bh = g % 48;
    const int qrow0 = tile * 64 + w * 16;
    const int nIter = (tile + 2) >> 1;

    const unsigned short* Qb = Q + (size_t)bh * S_ * HD;
    const unsigned short* Kb = Kd + (size_t)bh * S_ * HD;
    const unsigned short* Vb = Vt + (size_t)bh * HD * S_;

    const int srK = t >> 3, ssK = t & 7;
    const int kws = ((ssK ^ (srK & 7)) << 3);
    const int srV = t >> 4, ssV = t & 15;
    const int vs1 = (ssV >> 2) * 4 + (ssV & 1) * 2;
    const int voff = ((ssV >> 1) & 1) * 4;
    const int vws1 = ((vs1 ^ srV) << 3) + voff;
    const int vws2 = (((vs1 + 1) ^ srV) << 3) + voff;
    const int r7 = lr & 7;

    const unsigned short* KbS = Kb + (size_t)srK * HD + ssK * 8;
    const unsigned short* VbS = Vb + (size_t)srV * S_ + ssV * 8;

    bf16x8 aq0, aq1;
    aq0 = *reinterpret_cast<const bf16x8*>(Qb + (size_t)(qrow0 + lr) * HD + lc * 8);
    aq1 = *reinterpret_cast<const bf16x8*>(Qb + (size_t)(qrow0 + lr) * HD + 32 + lc * 8);

    f32x4 o[4] = {};
    float m = -INFINITY, l = 0.f;
    const int bb = bh / HEADS, hh = bh - bb * HEADS;
    const int qrow = qrow0 + lr;

    bf16x8 kreg[4], vreg[4];
#pragma unroll
    for (int i = 0; i < 4; i++) {
        kreg[i] = *reinterpret_cast<const bf16x8*>(KbS + i * 32 * HD);
        vreg[i] = *reinterpret_cast<const bf16x8*>(VbS + i * 16 * S_);
    }

    for (int it = 0; it < nIter; ++it) {
        __syncthreads();
#pragma unroll
        for (int i = 0; i < 4; i++) {
            *reinterpret_cast<bf16x8*>(&Ksh[(srK + i * 32) * 64 + kws]) = kreg[i];
            union { bf16x8 v; bf16x4 h[2]; } u2;
            u2.v = vreg[i];
            const int vrow = (srV + i * 16) * 128;
            *reinterpret_cast<bf16x4*>(&Vsh[vrow + vws1]) = u2.h[0];
            *reinterpret_cast<bf16x4*>(&Vsh[vrow + vws2]) = u2.h[1];
        }
        __syncthreads();

        if (it + 1 < nIter) {
            const int nkv0 = (it + 1) * 128;
#pragma unroll
            for (int i = 0; i < 4; i++) {
                kreg[i] = *reinterpret_cast<const bf16x8*>(KbS + (size_t)nkv0 * HD + i * 32 * HD);
                vreg[i] = *reinterpret_cast<const bf16x8*>(VbS + nkv0 + i * 16 * S_);
            }
        }

        const int kv0 = it * 128;
        const bool needMask = (it == nIter - 1);

        float p[8][4];
#pragma unroll
        for (int kt = 0; kt < 8; kt++) {
            const int row = kt * 16 + lr;
            const bf16x8 bk0 = *reinterpret_cast<const bf16x8*>(&Ksh[row * 64 + ((lc ^ r7) << 3)]);
            const bf16x8 bk1 = *reinterpret_cast<const bf16x8*>(&Ksh[row * 64 + (((4 + lc) ^ r7) << 3)]);
            f32x4 s = {};
            s = __builtin_amdgcn_mfma_f32_16x16x32_bf16(bk0, aq0, s, 0, 0, 0);
            s = __builtin_amdgcn_mfma_f32_16x16x32_bf16(bk1, aq1, s, 0, 0, 0);
#pragma unroll
            for (int r = 0; r < 4; r++) p[kt][r] = s[r];
        }
        if (needMask) {
#pragma unroll
            for (int kt = 0; kt < 8; kt++) {
                const int kbase = kv0 + kt * 16 + lc * 4;
#pragma unroll
                for (int r = 0; r < 4; r++)
                    if (kbase + r > qrow) p[kt][r] = -1e30f;
            }
        }

        float rm = -1e30f;
#pragma unroll
        for (int kt = 0; kt < 8; kt++)
#pragma unroll
            for (int r = 0; r < 4; r++) rm = fmaxf(rm, p[kt][r]);
        rm = fmaxf(rm, __shfl_xor(rm, 16));
        rm = fmaxf(rm, __shfl_xor(rm, 32));

        const bool grow = !__all(rm <= m);
        float mn = m, sc;
        if (grow) {
            mn = fmaxf(m, rm);
            sc = fexp2(m - mn);
        }

        float rs = 0.f;
#pragma unroll
        for (int kt = 0; kt < 8; kt++)
#pragma unroll
            for (int r = 0; r < 4; r++) {
                float e = fexp2(p[kt][r] - mn);
                p[kt][r] = e; rs += e;
            }
        rs += __shfl_xor(rs, 16);
        rs += __shfl_xor(rs, 32);

        if (grow) {
            l = l * sc + rs;
            m = mn;
            float scq[4];
#pragma unroll
            for (int r = 0; r < 4; r++) scq[r] = __shfl(sc, lc * 4 + r);
#pragma unroll
            for (int dt = 0; dt < 4; dt++)
#pragma unroll
                for (int r = 0; r < 4; r++) o[dt][r] *= scq[r];
        } else {
            l += rs;
        }

        bf16x8 ap[4];
#pragma unroll
        for (int kc = 0; kc < 4; kc++) {
            union { bf16x8 v; __bf16 b[8]; } u2;
            u2.b[0] = (__bf16)p[2 * kc][0];     u2.b[1] = (__bf16)p[2 * kc][1];
            u2.b[2] = (__bf16)p[2 * kc][2];     u2.b[3] = (__bf16)p[2 * kc][3];
            u2.b[4] = (__bf16)p[2 * kc + 1][0]; u2.b[5] = (__bf16)p[2 * kc + 1][1];
            u2.b[6] = (__bf16)p[2 * kc + 1][2]; u2.b[7] = (__bf16)p[2 * kc + 1][3];
            ap[kc] = u2.v;
        }

#pragma unroll
        for (int dt = 0; dt < 4; dt++) {
            const int row = dt * 16 + lr;
#pragma unroll
            for (int kc = 0; kc < 4; kc++) {
                const bf16x8 bv = *reinterpret_cast<const bf16x8*>(
                    &Vsh[row * 128 + (((kc * 4 + lc) ^ lr) << 3)]);
                o[dt] = __builtin_amdgcn_mfma_f32_16x16x32_bf16(ap[kc], bv, o[dt], 0, 0, 0);
            }
        }
    }

    {
        float lq[4];
#pragma unroll
        for (int r = 0; r < 4; r++) lq[r] = __shfl(l, lc * 4 + r);
#pragma unroll
        for (int r = 0; r < 4; r++) {
            float inv = 1.f / lq[r];
            int qr = qrow0 + lc * 4 + r;
#pragma unroll
            for (int dt = 0; dt < 4; dt++)
                O[((size_t)(bb * S_ + qr)) * E_ + hh * HD + dt * 16 + lr] = f2bf(o[dt][r] * inv);
        }
    }
}

extern "C" void kernel_launch(void* const* d_in, const int* in_sizes, int n_in,
                              void* d_out, int out_size, void* d_ws, size_t ws_size,
                              hipStream_t stream) {
    const float* x      = (const float*)d_in[0];
    const float* w_attn = (const float*)d_in[1];
    const float* b_attn = (const float*)d_in[2];
    const float* w_proj = (const float*)d_in[3];
    const float* b_proj = (const float*)d_in[4];
    float* out = (float*)d_out;

    char* ws = (char*)d_ws;
    const size_t M = (size_t)B_ * S_;             // 8192
    unsigned short* xb  = (unsigned short*)(ws);                         // 8192*768
    unsigned short* waT = (unsigned short*)(ws + 12582912);              // 2304*768
    unsigned short* wpT = (unsigned short*)(ws + 16121856);              // 768*768
    unsigned short* Qb  = (unsigned short*)(ws + 17301504);              // BH*S*D
    unsigned short* Kb  = (unsigned short*)(ws + 29884416);
    unsigned short* Vt  = (unsigned short*)(ws + 42467328);
    unsigned short* AO  = (unsigned short*)(ws + 55050240);              // 8192*768

    int n4 = (int)(M * E_ / 4);
    cvt_kernel<<<(n4 + 255) / 256, 256, 0, stream>>>(x, xb, n4);
    transpose_cvt<<<dim3(3 * E_ / 32, E_ / 32), dim3(32, 32), 0, stream>>>(w_attn, waT, E_, 3 * E_);
    transpose_cvt<<<dim3(E_ / 32, E_ / 32), dim3(32, 32), 0, stream>>>(w_proj, wpT, E_, E_);

    gemm16<0><<<2304, 256, 0, stream>>>(
        xb, waT, b_attn, Qb, Kb, Vt, nullptr, (int)M, 3 * E_, E_);

    attn_kernel<<<1536, 256, 0, stream>>>(Qb, Kb, Vt, AO);

    gemm16<1><<<768, 256, 0, stream>>>(
        AO, wpT, b_proj, nullptr, nullptr, nullptr, out, (int)M, E_, E_);
}

// Round 23
// 147.610 us; speedup vs baseline: 1.1331x; 1.0793x over previous
//
#include <hip/hip_runtime.h>
#include <hip/hip_bf16.h>

typedef __attribute__((ext_vector_type(8))) __bf16 bf16x8;
typedef __attribute__((ext_vector_type(4))) __bf16 bf16x4;
typedef __attribute__((ext_vector_type(4))) float f32x4;

#define E_ 768
#define HEADS 12
#define HD 64
#define S_ 2048
#define B_ 4

__device__ inline unsigned short f2bf(float f) {
    union { float f; unsigned int u; } x{f};
    unsigned int r = x.u + 0x7FFFu + ((x.u >> 16) & 1u);
    return (unsigned short)(r >> 16);
}

__device__ inline float fexp2(float x) { return __builtin_amdgcn_exp2f(x); }

// ---------- fp32 -> bf16 elementwise (x) ----------
__global__ void cvt_kernel(const float* __restrict__ in, unsigned short* __restrict__ out, int n4) {
    int i = blockIdx.x * blockDim.x + threadIdx.x;
    if (i < n4) {
        float4 v = reinterpret_cast<const float4*>(in)[i];
        ushort4 o;
        o.x = f2bf(v.x); o.y = f2bf(v.y); o.z = f2bf(v.z); o.w = f2bf(v.w);
        reinterpret_cast<ushort4*>(out)[i] = o;
    }
}

// ---------- transpose + convert: w[K][N] fp32 -> wT[N][K] bf16 ----------
__global__ void transpose_cvt(const float* __restrict__ w, unsigned short* __restrict__ wT,
                              int K, int N) {
    __shared__ float tile[32][33];
    int n0 = blockIdx.x * 32, k0 = blockIdx.y * 32;
    int tx = threadIdx.x, ty = threadIdx.y;
    tile[ty][tx] = w[(size_t)(k0 + ty) * N + n0 + tx];
    __syncthreads();
    wT[(size_t)(n0 + ty) * K + k0 + tx] = f2bf(tile[tx][ty]);
}

// ---------- bf16 MFMA GEMM, m97 structure, BN=64, XCD-chunked swizzle ----------
// MODE 0: qkv. Q pre-scaled by 0.125*log2e. Outputs restaged in LDS for
//         coalesced stores (V transposed along s; Q/K row-major along d).
// MODE 1: fp32 out + bias.
template<int MODE>
__global__ __launch_bounds__(256) void gemm16(
    const unsigned short* __restrict__ A, const unsigned short* __restrict__ Bt,
    const float* __restrict__ bias,
    unsigned short* __restrict__ Qo, unsigned short* __restrict__ Ko,
    unsigned short* __restrict__ Vt, float* __restrict__ Of,
    int M, int N, int K)
{
    constexpr int BN = 64;
    constexpr int NJ = 2;
    __shared__ unsigned short Sh[128 * 64 + 64 * 64];   // A-tile + B-tile = 24 KB
    unsigned short* Ash = Sh;
    unsigned short* Bsh = Sh + 128 * 64;

    const int nbx = N / BN;
    const int nwg = (M >> 7) * nbx;
    const int cpx = nwg >> 3;
    const int orig = blockIdx.x;
    const int wgid = (orig & 7) * cpx + (orig >> 3);   // XCD-chunked (nwg%8==0)
    const int row0 = (wgid / nbx) * 128;
    const int col0 = (wgid % nbx) * BN;

    const int t = threadIdx.x;
    const int w = t >> 6, lane = t & 63;
    const int lr = lane & 15, lc = lane >> 4;
    const int wrow = (w >> 1) * 64;
    const int wcol = (w & 1) * 32;

    const int srow = lane >> 3;
    const int sslot = lane & 7;

    f32x4 acc[4][NJ] = {};

    for (int k0 = 0; k0 < K; k0 += 64) {
#pragma unroll
        for (int j = 0; j < 4; j++) {
            const int rbase = j * 32 + w * 8;
            const unsigned short* ga = A + (size_t)(row0 + rbase + srow) * K + k0 + sslot * 8;
            __builtin_amdgcn_global_load_lds(
                (const __attribute__((address_space(1))) void*)ga,
                (__attribute__((address_space(3))) void*)&Ash[rbase * 64], 16, 0, 0);
        }
#pragma unroll
        for (int j = 0; j < NJ; j++) {
            const int rbase = j * 32 + w * 8;
            const unsigned short* gb = Bt + (size_t)(col0 + rbase + srow) * K + k0 + sslot * 8;
            __builtin_amdgcn_global_load_lds(
                (const __attribute__((address_space(1))) void*)gb,
                (__attribute__((address_space(3))) void*)&Bsh[rbase * 64], 16, 0, 0);
        }
        __syncthreads();

#pragma unroll
        for (int ks = 0; ks < 2; ks++) {
            bf16x8 a[4], b[NJ];
#pragma unroll
            for (int i = 0; i < 4; i++)
                a[i] = *reinterpret_cast<const bf16x8*>(&Ash[(wrow + i * 16 + lr) * 64 + ks * 32 + lc * 8]);
#pragma unroll
            for (int j2 = 0; j2 < NJ; j2++)
                b[j2] = *reinterpret_cast<const bf16x8*>(&Bsh[(wcol + j2 * 16 + lr) * 64 + ks * 32 + lc * 8]);
#pragma unroll
            for (int i = 0; i < 4; i++)
#pragma unroll
                for (int j2 = 0; j2 < NJ; j2++)
                    acc[i][j2] = __builtin_amdgcn_mfma_f32_16x16x32_bf16(a[i], b[j2], acc[i][j2], 0, 0, 0);
        }
        __syncthreads();
    }

    if constexpr (MODE == 0) {
        const int bb = row0 >> 11;
        const int s0 = row0 & (S_ - 1);
        const int which = col0 / E_;                   // 0=Q, 1=K, 2=V (uniform per block)
        const int h = (col0 - which * E_) >> 6;        // single head per block
        const size_t bh = (size_t)(bb * HEADS + h);
        if (which == 2) {
            // ---- V: transpose-restage -> 256B stores along s ----
#pragma unroll
            for (int i = 0; i < 4; i++)
#pragma unroll
                for (int j = 0; j < NJ; j++) {
                    const int c = wcol + j * 16 + lr;
                    const float bv = bias[col0 + c];
#pragma unroll
                    for (int r = 0; r < 4; r++) {
                        const int row = wrow + i * 16 + lc * 4 + r;
                        Sh[c * 128 + (row ^ ((c & 15) << 3))] = f2bf(acc[i][j][r] + bv);
                    }
                }
            __syncthreads();
#pragma unroll
            for (int pass = 0; pass < 4; pass++) {
                const int c = pass * 16 + (t >> 4);    // 0..63 (= d)
                const int sL = (t & 15) * 8;           // 0..120
                bf16x8 vv = *reinterpret_cast<const bf16x8*>(&Sh[c * 128 + (sL ^ ((c & 15) << 3))]);
                *reinterpret_cast<bf16x8*>(&Vt[(bh * HD + c) * S_ + s0 + sL]) = vv;
            }
            return;
        }
        // ---- Q/K: row-major restage -> 128B stores along d ----
        const float qsc = (which == 0) ? 0.18033688f : 1.0f;   // 0.125*log2e into Q
        unsigned short* dst = (which == 0) ? Qo : Ko;
#pragma unroll
        for (int i = 0; i < 4; i++)
#pragma unroll
            for (int j = 0; j < NJ; j++) {
                const int c = wcol + j * 16 + lr;
                const float bv = bias[col0 + c];
#pragma unroll
                for (int r = 0; r < 4; r++) {
                    const int row = wrow + i * 16 + lc * 4 + r;
                    Sh[row * 64 + (c ^ ((row & 7) << 3))] = f2bf((acc[i][j][r] + bv) * qsc);
                }
            }
        __syncthreads();
#pragma unroll
        for (int pass = 0; pass < 4; pass++) {
            const int row = pass * 32 + (t >> 3);      // 0..127 (s offset)
            const int c2 = (t & 7) * 8;                // 0..56 (= d base)
            bf16x8 vv = *reinterpret_cast<const bf16x8*>(&Sh[row * 64 + (c2 ^ ((row & 7) << 3))]);
            *reinterpret_cast<bf16x8*>(&dst[(bh * S_ + s0 + row) * HD + c2]) = vv;
        }
    } else {
#pragma unroll
        for (int i = 0; i < 4; i++)
#pragma unroll
            for (int j = 0; j < NJ; j++) {
                int col = col0 + wcol + j * 16 + lr;
                float bv = bias[col];
#pragma unroll
                for (int r = 0; r < 4; r++) {
                    int row = row0 + wrow + i * 16 + lc * 4 + r;
                    Of[(size_t)row * N + col] = acc[i][j][r] + bv;
                }
            }
    }
}

// ---------- causal flash attention, one q-tile per block ----------
// grid 1536: tile = 31 - g/48 (LARGEST FIRST — R20 verified; R22's interleave
// regressed 63.7->76.9us, reverted). bh = g%48. Block = 4 waves, nIter =
// (tile+2)>>1 KV-128 iterations. Inner loop: swapped QK^T, exp2-domain R6
// softmax + exact rescale-skip, reg-P PV with permuted-layout Vsh, mask only
// on the final iteration.
__global__ __launch_bounds__(256) void attn_kernel(
    const unsigned short* __restrict__ Q, const unsigned short* __restrict__ Kd,
    const unsigned short* __restrict__ Vt, unsigned short* __restrict__ O)
{
    __shared__ unsigned short Ksh[128 * 64];
    __shared__ unsigned short Vsh[64 * 128];

    const int t = threadIdx.x;
    const int w = t >> 6, lane = t & 63;
    const int lr = lane & 15, lc = lane >> 4;
    const int g = blockIdx.x;
    const int tile = 31 - g / 48;          // largest tiles dispatch first
    const int bh = g % 48;
    const int qrow0 = tile * 64 + w * 16;
    const int nIter = (tile + 2) >> 1;

    const unsigned short* Qb = Q + (size_t)bh * S_ * HD;
    const unsigned short* Kb = Kd + (size_t)bh * S_ * HD;
    const unsigned short* Vb = Vt + (size_t)bh * HD * S_;

    const int srK = t >> 3, ssK = t & 7;
    const int kws = ((ssK ^ (srK & 7)) << 3);
    const int srV = t >> 4, ssV = t & 15;
    const int vs1 = (ssV >> 2) * 4 + (ssV & 1) * 2;
    const int voff = ((ssV >> 1) & 1) * 4;
    const int vws1 = ((vs1 ^ srV) << 3) + voff;
    const int vws2 = (((vs1 + 1) ^ srV) << 3) + voff;
    const int r7 = lr & 7;

    const unsigned short* KbS = Kb + (size_t)srK * HD + ssK * 8;
    const unsigned short* VbS = Vb + (size_t)srV * S_ + ssV * 8;

    bf16x8 aq0, aq1;
    aq0 = *reinterpret_cast<const bf16x8*>(Qb + (size_t)(qrow0 + lr) * HD + lc * 8);
    aq1 = *reinterpret_cast<const bf16x8*>(Qb + (size_t)(qrow0 + lr) * HD + 32 + lc * 8);

    f32x4 o[4] = {};
    float m = -INFINITY, l = 0.f;
    const int bb = bh / HEADS, hh = bh - bb * HEADS;
    const int qrow = qrow0 + lr;

    bf16x8 kreg[4], vreg[4];
#pragma unroll
    for (int i = 0; i < 4; i++) {
        kreg[i] = *reinterpret_cast<const bf16x8*>(KbS + i * 32 * HD);
        vreg[i] = *reinterpret_cast<const bf16x8*>(VbS + i * 16 * S_);
    }

    for (int it = 0; it < nIter; ++it) {
        __syncthreads();
#pragma unroll
        for (int i = 0; i < 4; i++) {
            *reinterpret_cast<bf16x8*>(&Ksh[(srK + i * 32) * 64 + kws]) = kreg[i];
            union { bf16x8 v; bf16x4 h[2]; } u2;
            u2.v = vreg[i];
            const int vrow = (srV + i * 16) * 128;
            *reinterpret_cast<bf16x4*>(&Vsh[vrow + vws1]) = u2.h[0];
            *reinterpret_cast<bf16x4*>(&Vsh[vrow + vws2]) = u2.h[1];
        }
        __syncthreads();

        if (it + 1 < nIter) {
            const int nkv0 = (it + 1) * 128;
#pragma unroll
            for (int i = 0; i < 4; i++) {
                kreg[i] = *reinterpret_cast<const bf16x8*>(KbS + (size_t)nkv0 * HD + i * 32 * HD);
                vreg[i] = *reinterpret_cast<const bf16x8*>(VbS + nkv0 + i * 16 * S_);
            }
        }

        const int kv0 = it * 128;
        const bool needMask = (it == nIter - 1);

        float p[8][4];
#pragma unroll
        for (int kt = 0; kt < 8; kt++) {
            const int row = kt * 16 + lr;
            const bf16x8 bk0 = *reinterpret_cast<const bf16x8*>(&Ksh[row * 64 + ((lc ^ r7) << 3)]);
            const bf16x8 bk1 = *reinterpret_cast<const bf16x8*>(&Ksh[row * 64 + (((4 + lc) ^ r7) << 3)]);
            f32x4 s = {};
            s = __builtin_amdgcn_mfma_f32_16x16x32_bf16(bk0, aq0, s, 0, 0, 0);
            s = __builtin_amdgcn_mfma_f32_16x16x32_bf16(bk1, aq1, s, 0, 0, 0);
#pragma unroll
            for (int r = 0; r < 4; r++) p[kt][r] = s[r];
        }
        if (needMask) {
#pragma unroll
            for (int kt = 0; kt < 8; kt++) {
                const int kbase = kv0 + kt * 16 + lc * 4;
#pragma unroll
                for (int r = 0; r < 4; r++)
                    if (kbase + r > qrow) p[kt][r] = -1e30f;
            }
        }

        float rm = -1e30f;
#pragma unroll
        for (int kt = 0; kt < 8; kt++)
#pragma unroll
            for (int r = 0; r < 4; r++) rm = fmaxf(rm, p[kt][r]);
        rm = fmaxf(rm, __shfl_xor(rm, 16));
        rm = fmaxf(rm, __shfl_xor(rm, 32));

        const bool grow = !__all(rm <= m);
        float mn = m, sc;
        if (grow) {
            mn = fmaxf(m, rm);
            sc = fexp2(m - mn);
        }

        float rs = 0.f;
#pragma unroll
        for (int kt = 0; kt < 8; kt++)
#pragma unroll
            for (int r = 0; r < 4; r++) {
                float e = fexp2(p[kt][r] - mn);
                p[kt][r] = e; rs += e;
            }
        rs += __shfl_xor(rs, 16);
        rs += __shfl_xor(rs, 32);

        if (grow) {
            l = l * sc + rs;
            m = mn;
            float scq[4];
#pragma unroll
            for (int r = 0; r < 4; r++) scq[r] = __shfl(sc, lc * 4 + r);
#pragma unroll
            for (int dt = 0; dt < 4; dt++)
#pragma unroll
                for (int r = 0; r < 4; r++) o[dt][r] *= scq[r];
        } else {
            l += rs;
        }

        bf16x8 ap[4];
#pragma unroll
        for (int kc = 0; kc < 4; kc++) {
            union { bf16x8 v; __bf16 b[8]; } u2;
            u2.b[0] = (__bf16)p[2 * kc][0];     u2.b[1] = (__bf16)p[2 * kc][1];
            u2.b[2] = (__bf16)p[2 * kc][2];     u2.b[3] = (__bf16)p[2 * kc][3];
            u2.b[4] = (__bf16)p[2 * kc + 1][0]; u2.b[5] = (__bf16)p[2 * kc + 1][1];
            u2.b[6] = (__bf16)p[2 * kc + 1][2]; u2.b[7] = (__bf16)p[2 * kc + 1][3];
            ap[kc] = u2.v;
        }

#pragma unroll
        for (int dt = 0; dt < 4; dt++) {
            const int row = dt * 16 + lr;
#pragma unroll
            for (int kc = 0; kc < 4; kc++) {
                const bf16x8 bv = *reinterpret_cast<const bf16x8*>(
                    &Vsh[row * 128 + (((kc * 4 + lc) ^ lr) << 3)]);
                o[dt] = __builtin_amdgcn_mfma_f32_16x16x32_bf16(ap[kc], bv, o[dt], 0, 0, 0);
            }
        }
    }

    {
        float lq[4];
#pragma unroll
        for (int r = 0; r < 4; r++) lq[r] = __shfl(l, lc * 4 + r);
#pragma unroll
        for (int r = 0; r < 4; r++) {
            float inv = 1.f / lq[r];
            int qr = qrow0 + lc * 4 + r;
#pragma unroll
            for (int dt = 0; dt < 4; dt++)
                O[((size_t)(bb * S_ + qr)) * E_ + hh * HD + dt * 16 + lr] = f2bf(o[dt][r] * inv);
        }
    }
}

extern "C" void kernel_launch(void* const* d_in, const int* in_sizes, int n_in,
                              void* d_out, int out_size, void* d_ws, size_t ws_size,
                              hipStream_t stream) {
    const float* x      = (const float*)d_in[0];
    const float* w_attn = (const float*)d_in[1];
    const float* b_attn = (const float*)d_in[2];
    const float* w_proj = (const float*)d_in[3];
    const float* b_proj = (const float*)d_in[4];
    float* out = (float*)d_out;

    char* ws = (char*)d_ws;
    const size_t M = (size_t)B_ * S_;             // 8192
    unsigned short* xb  = (unsigned short*)(ws);                         // 8192*768
    unsigned short* waT = (unsigned short*)(ws + 12582912);              // 2304*768
    unsigned short* wpT = (unsigned short*)(ws + 16121856);              // 768*768
    unsigned short* Qb  = (unsigned short*)(ws + 17301504);              // BH*S*D
    unsigned short* Kb  = (unsigned short*)(ws + 29884416);
    unsigned short* Vt  = (unsigned short*)(ws + 42467328);
    unsigned short* AO  = (unsigned short*)(ws + 55050240);              // 8192*768

    int n4 = (int)(M * E_ / 4);
    cvt_kernel<<<(n4 + 255) / 256, 256, 0, stream>>>(x, xb, n4);
    transpose_cvt<<<dim3(3 * E_ / 32, E_ / 32), dim3(32, 32), 0, stream>>>(w_attn, waT, E_, 3 * E_);
    transpose_cvt<<<dim3(E_ / 32, E_ / 32), dim3(32, 32), 0, stream>>>(w_proj, wpT, E_, E_);

    gemm16<0><<<2304, 256, 0, stream>>>(
        xb, waT, b_attn, Qb, Kb, Vt, nullptr, (int)M, 3 * E_, E_);

    attn_kernel<<<1536, 256, 0, stream>>>(Qb, Kb, Vt, AO);

    gemm16<1><<<768, 256, 0, stream>>>(
        AO, wpT, b_proj, nullptr, nullptr, nullptr, out, (int)M, E_, E_);
}

// Round 24
// 141.593 us; speedup vs baseline: 1.1812x; 1.0425x over previous
//
#include <hip/hip_runtime.h>
#include <hip/hip_bf16.h>

typedef __attribute__((ext_vector_type(8))) __bf16 bf16x8;
typedef __attribute__((ext_vector_type(4))) __bf16 bf16x4;
typedef __attribute__((ext_vector_type(4))) float f32x4;

#define E_ 768
#define HEADS 12
#define HD 64
#define S_ 2048
#define B_ 4

__device__ inline unsigned short f2bf(float f) {
    union { float f; unsigned int u; } x{f};
    unsigned int r = x.u + 0x7FFFu + ((x.u >> 16) & 1u);
    return (unsigned short)(r >> 16);
}

__device__ inline float fexp2(float x) { return __builtin_amdgcn_exp2f(x); }

// ---------- fp32 -> bf16 elementwise (x) ----------
__global__ void cvt_kernel(const float* __restrict__ in, unsigned short* __restrict__ out, int n4) {
    int i = blockIdx.x * blockDim.x + threadIdx.x;
    if (i < n4) {
        float4 v = reinterpret_cast<const float4*>(in)[i];
        ushort4 o;
        o.x = f2bf(v.x); o.y = f2bf(v.y); o.z = f2bf(v.z); o.w = f2bf(v.w);
        reinterpret_cast<ushort4*>(out)[i] = o;
    }
}

// ---------- transpose + convert: w[K][N] fp32 -> wT[N][K] bf16 ----------
__global__ void transpose_cvt(const float* __restrict__ w, unsigned short* __restrict__ wT,
                              int K, int N) {
    __shared__ float tile[32][33];
    int n0 = blockIdx.x * 32, k0 = blockIdx.y * 32;
    int tx = threadIdx.x, ty = threadIdx.y;
    tile[ty][tx] = w[(size_t)(k0 + ty) * N + n0 + tx];
    __syncthreads();
    wT[(size_t)(n0 + ty) * K + k0 + tx] = f2bf(tile[tx][ty]);
}

// ---------- bf16 MFMA GEMM, BN=64, T3-min DOUBLE-BUFFERED K-loop ----------
// Stage tile t+1 into buf^1 BEFORE computing tile t from buf; one
// vmcnt(0)+barrier per K-step (load latency hides under compute).
// MODE 0: qkv. Q pre-scaled by 0.125*log2e. Outputs restaged in LDS for
//         coalesced stores (V transposed along s; Q/K row-major along d).
// MODE 1: fp32 out + bias.
template<int MODE>
__global__ __launch_bounds__(256) void gemm16(
    const unsigned short* __restrict__ A, const unsigned short* __restrict__ Bt,
    const float* __restrict__ bias,
    unsigned short* __restrict__ Qo, unsigned short* __restrict__ Ko,
    unsigned short* __restrict__ Vt, float* __restrict__ Of,
    int M, int N, int K)
{
    constexpr int BN = 64;
    constexpr int NJ = 2;
    __shared__ unsigned short Sh[2][128 * 64 + 64 * 64];   // 2 x 24 KB = 48 KB
    unsigned short* Shf = &Sh[0][0];

    const int nbx = N / BN;
    const int nwg = (M >> 7) * nbx;
    const int cpx = nwg >> 3;
    const int orig = blockIdx.x;
    const int wgid = (orig & 7) * cpx + (orig >> 3);   // XCD-chunked (nwg%8==0)
    const int row0 = (wgid / nbx) * 128;
    const int col0 = (wgid % nbx) * BN;

    const int t = threadIdx.x;
    const int w = t >> 6, lane = t & 63;
    const int lr = lane & 15, lc = lane >> 4;
    const int wrow = (w >> 1) * 64;
    const int wcol = (w & 1) * 32;

    const int srow = lane >> 3;
    const int sslot = lane & 7;

    f32x4 acc[4][NJ] = {};

    auto stage = [&](int buf, int k0) {
        unsigned short* Ad = &Sh[buf][0];
        unsigned short* Bd = &Sh[buf][128 * 64];
#pragma unroll
        for (int j = 0; j < 4; j++) {
            const int rbase = j * 32 + w * 8;
            const unsigned short* ga = A + (size_t)(row0 + rbase + srow) * K + k0 + sslot * 8;
            __builtin_amdgcn_global_load_lds(
                (const __attribute__((address_space(1))) void*)ga,
                (__attribute__((address_space(3))) void*)&Ad[rbase * 64], 16, 0, 0);
        }
#pragma unroll
        for (int j = 0; j < NJ; j++) {
            const int rbase = j * 32 + w * 8;
            const unsigned short* gb = Bt + (size_t)(col0 + rbase + srow) * K + k0 + sslot * 8;
            __builtin_amdgcn_global_load_lds(
                (const __attribute__((address_space(1))) void*)gb,
                (__attribute__((address_space(3))) void*)&Bd[rbase * 64], 16, 0, 0);
        }
    };

    // prologue: tile 0 -> buf 0
    stage(0, 0);
    asm volatile("s_waitcnt vmcnt(0)" ::: "memory");
    __syncthreads();

    int cur = 0;
    for (int k0 = 0; k0 < K; k0 += 64) {
        if (k0 + 64 < K) stage(cur ^ 1, k0 + 64);   // issue next tile EARLY

        const unsigned short* Ac = &Sh[cur][0];
        const unsigned short* Bc = &Sh[cur][128 * 64];
#pragma unroll
        for (int ks = 0; ks < 2; ks++) {
            bf16x8 a[4], b[NJ];
#pragma unroll
            for (int i = 0; i < 4; i++)
                a[i] = *reinterpret_cast<const bf16x8*>(&Ac[(wrow + i * 16 + lr) * 64 + ks * 32 + lc * 8]);
#pragma unroll
            for (int j2 = 0; j2 < NJ; j2++)
                b[j2] = *reinterpret_cast<const bf16x8*>(&Bc[(wcol + j2 * 16 + lr) * 64 + ks * 32 + lc * 8]);
#pragma unroll
            for (int i = 0; i < 4; i++)
#pragma unroll
                for (int j2 = 0; j2 < NJ; j2++)
                    acc[i][j2] = __builtin_amdgcn_mfma_f32_16x16x32_bf16(a[i], b[j2], acc[i][j2], 0, 0, 0);
        }
        asm volatile("s_waitcnt vmcnt(0)" ::: "memory");
        __syncthreads();
        cur ^= 1;
    }

    if constexpr (MODE == 0) {
        const int bb = row0 >> 11;
        const int s0 = row0 & (S_ - 1);
        const int which = col0 / E_;                   // 0=Q, 1=K, 2=V (uniform per block)
        const int h = (col0 - which * E_) >> 6;        // single head per block
        const size_t bh = (size_t)(bb * HEADS + h);
        if (which == 2) {
            // ---- V: transpose-restage -> 256B stores along s ----
#pragma unroll
            for (int i = 0; i < 4; i++)
#pragma unroll
                for (int j = 0; j < NJ; j++) {
                    const int c = wcol + j * 16 + lr;
                    const float bv = bias[col0 + c];
#pragma unroll
                    for (int r = 0; r < 4; r++) {
                        const int row = wrow + i * 16 + lc * 4 + r;
                        Shf[c * 128 + (row ^ ((c & 15) << 3))] = f2bf(acc[i][j][r] + bv);
                    }
                }
            __syncthreads();
#pragma unroll
            for (int pass = 0; pass < 4; pass++) {
                const int c = pass * 16 + (t >> 4);    // 0..63 (= d)
                const int sL = (t & 15) * 8;           // 0..120
                bf16x8 vv = *reinterpret_cast<const bf16x8*>(&Shf[c * 128 + (sL ^ ((c & 15) << 3))]);
                *reinterpret_cast<bf16x8*>(&Vt[(bh * HD + c) * S_ + s0 + sL]) = vv;
            }
            return;
        }
        // ---- Q/K: row-major restage -> 128B stores along d ----
        const float qsc = (which == 0) ? 0.18033688f : 1.0f;   // 0.125*log2e into Q
        unsigned short* dst = (which == 0) ? Qo : Ko;
#pragma unroll
        for (int i = 0; i < 4; i++)
#pragma unroll
            for (int j = 0; j < NJ; j++) {
                const int c = wcol + j * 16 + lr;
                const float bv = bias[col0 + c];
#pragma unroll
                for (int r = 0; r < 4; r++) {
                    const int row = wrow + i * 16 + lc * 4 + r;
                    Shf[row * 64 + (c ^ ((row & 7) << 3))] = f2bf((acc[i][j][r] + bv) * qsc);
                }
            }
        __syncthreads();
#pragma unroll
        for (int pass = 0; pass < 4; pass++) {
            const int row = pass * 32 + (t >> 3);      // 0..127 (s offset)
            const int c2 = (t & 7) * 8;                // 0..56 (= d base)
            bf16x8 vv = *reinterpret_cast<const bf16x8*>(&Shf[row * 64 + (c2 ^ ((row & 7) << 3))]);
            *reinterpret_cast<bf16x8*>(&dst[(bh * S_ + s0 + row) * HD + c2]) = vv;
        }
    } else {
#pragma unroll
        for (int i = 0; i < 4; i++)
#pragma unroll
            for (int j = 0; j < NJ; j++) {
                int col = col0 + wcol + j * 16 + lr;
                float bv = bias[col];
#pragma unroll
                for (int r = 0; r < 4; r++) {
                    int row = row0 + wrow + i * 16 + lc * 4 + r;
                    Of[(size_t)row * N + col] = acc[i][j][r] + bv;
                }
            }
    }
}

// ---------- causal flash attention, one q-tile per block (R23, verified) ----------
__global__ __launch_bounds__(256) void attn_kernel(
    const unsigned short* __restrict__ Q, const unsigned short* __restrict__ Kd,
    const unsigned short* __restrict__ Vt, unsigned short* __restrict__ O)
{
    __shared__ unsigned short Ksh[128 * 64];
    __shared__ unsigned short Vsh[64 * 128];

    const int t = threadIdx.x;
    const int w = t >> 6, lane = t & 63;
    const int lr = lane & 15, lc = lane >> 4;
    const int g = blockIdx.x;
    const int tile = 31 - g / 48;          // largest tiles dispatch first
    const int bh = g % 48;
    const int qrow0 = tile * 64 + w * 16;
    const int nIter = (tile + 2) >> 1;

    const unsigned short* Qb = Q + (size_t)bh * S_ * HD;
    const unsigned short* Kb = Kd + (size_t)bh * S_ * HD;
    const unsigned short* Vb = Vt + (size_t)bh * HD * S_;

    const int srK = t >> 3, ssK = t & 7;
    const int kws = ((ssK ^ (srK & 7)) << 3);
    const int srV = t >> 4, ssV = t & 15;
    const int vs1 = (ssV >> 2) * 4 + (ssV & 1) * 2;
    const int voff = ((ssV >> 1) & 1) * 4;
    const int vws1 = ((vs1 ^ srV) << 3) + voff;
    const int vws2 = (((vs1 + 1) ^ srV) << 3) + voff;
    const int r7 = lr & 7;

    const unsigned short* KbS = Kb + (size_t)srK * HD + ssK * 8;
    const unsigned short* VbS = Vb + (size_t)srV * S_ + ssV * 8;

    bf16x8 aq0, aq1;
    aq0 = *reinterpret_cast<const bf16x8*>(Qb + (size_t)(qrow0 + lr) * HD + lc * 8);
    aq1 = *reinterpret_cast<const bf16x8*>(Qb + (size_t)(qrow0 + lr) * HD + 32 + lc * 8);

    f32x4 o[4] = {};
    float m = -INFINITY, l = 0.f;
    const int bb = bh / HEADS, hh = bh - bb * HEADS;
    const int qrow = qrow0 + lr;

    bf16x8 kreg[4], vreg[4];
#pragma unroll
    for (int i = 0; i < 4; i++) {
        kreg[i] = *reinterpret_cast<const bf16x8*>(KbS + i * 32 * HD);
        vreg[i] = *reinterpret_cast<const bf16x8*>(VbS + i * 16 * S_);
    }

    for (int it = 0; it < nIter; ++it) {
        __syncthreads();
#pragma unroll
        for (int i = 0; i < 4; i++) {
            *reinterpret_cast<bf16x8*>(&Ksh[(srK + i * 32) * 64 + kws]) = kreg[i];
            union { bf16x8 v; bf16x4 h[2]; } u2;
            u2.v = vreg[i];
            const int vrow = (srV + i * 16) * 128;
            *reinterpret_cast<bf16x4*>(&Vsh[vrow + vws1]) = u2.h[0];
            *reinterpret_cast<bf16x4*>(&Vsh[vrow + vws2]) = u2.h[1];
        }
        __syncthreads();

        if (it + 1 < nIter) {
            const int nkv0 = (it + 1) * 128;
#pragma unroll
            for (int i = 0; i < 4; i++) {
                kreg[i] = *reinterpret_cast<const bf16x8*>(KbS + (size_t)nkv0 * HD + i * 32 * HD);
                vreg[i] = *reinterpret_cast<const bf16x8*>(VbS + nkv0 + i * 16 * S_);
            }
        }

        const int kv0 = it * 128;
        const bool needMask = (it == nIter - 1);

        float p[8][4];
#pragma unroll
        for (int kt = 0; kt < 8; kt++) {
            const int row = kt * 16 + lr;
            const bf16x8 bk0 = *reinterpret_cast<const bf16x8*>(&Ksh[row * 64 + ((lc ^ r7) << 3)]);
            const bf16x8 bk1 = *reinterpret_cast<const bf16x8*>(&Ksh[row * 64 + (((4 + lc) ^ r7) << 3)]);
            f32x4 s = {};
            s = __builtin_amdgcn_mfma_f32_16x16x32_bf16(bk0, aq0, s, 0, 0, 0);
            s = __builtin_amdgcn_mfma_f32_16x16x32_bf16(bk1, aq1, s, 0, 0, 0);
#pragma unroll
            for (int r = 0; r < 4; r++) p[kt][r] = s[r];
        }
        if (needMask) {
#pragma unroll
            for (int kt = 0; kt < 8; kt++) {
                const int kbase = kv0 + kt * 16 + lc * 4;
#pragma unroll
                for (int r = 0; r < 4; r++)
                    if (kbase + r > qrow) p[kt][r] = -1e30f;
            }
        }

        float rm = -1e30f;
#pragma unroll
        for (int kt = 0; kt < 8; kt++)
#pragma unroll
            for (int r = 0; r < 4; r++) rm = fmaxf(rm, p[kt][r]);
        rm = fmaxf(rm, __shfl_xor(rm, 16));
        rm = fmaxf(rm, __shfl_xor(rm, 32));

        const bool grow = !__all(rm <= m);
        float mn = m, sc;
        if (grow) {
            mn = fmaxf(m, rm);
            sc = fexp2(m - mn);
        }

        float rs = 0.f;
#pragma unroll
        for (int kt = 0; kt < 8; kt++)
#pragma unroll
            for (int r = 0; r < 4; r++) {
                float e = fexp2(p[kt][r] - mn);
                p[kt][r] = e; rs += e;
            }
        rs += __shfl_xor(rs, 16);
        rs += __shfl_xor(rs, 32);

        if (grow) {
            l = l * sc + rs;
            m = mn;
            float scq[4];
#pragma unroll
            for (int r = 0; r < 4; r++) scq[r] = __shfl(sc, lc * 4 + r);
#pragma unroll
            for (int dt = 0; dt < 4; dt++)
#pragma unroll
                for (int r = 0; r < 4; r++) o[dt][r] *= scq[r];
        } else {
            l += rs;
        }

        bf16x8 ap[4];
#pragma unroll
        for (int kc = 0; kc < 4; kc++) {
            union { bf16x8 v; __bf16 b[8]; } u2;
            u2.b[0] = (__bf16)p[2 * kc][0];     u2.b[1] = (__bf16)p[2 * kc][1];
            u2.b[2] = (__bf16)p[2 * kc][2];     u2.b[3] = (__bf16)p[2 * kc][3];
            u2.b[4] = (__bf16)p[2 * kc + 1][0]; u2.b[5] = (__bf16)p[2 * kc + 1][1];
            u2.b[6] = (__bf16)p[2 * kc + 1][2]; u2.b[7] = (__bf16)p[2 * kc + 1][3];
            ap[kc] = u2.v;
        }

#pragma unroll
        for (int dt = 0; dt < 4; dt++) {
            const int row = dt * 16 + lr;
#pragma unroll
            for (int kc = 0; kc < 4; kc++) {
                const bf16x8 bv = *reinterpret_cast<const bf16x8*>(
                    &Vsh[row * 128 + (((kc * 4 + lc) ^ lr) << 3)]);
                o[dt] = __builtin_amdgcn_mfma_f32_16x16x32_bf16(ap[kc], bv, o[dt], 0, 0, 0);
            }
        }
    }

    {
        float lq[4];
#pragma unroll
        for (int r = 0; r < 4; r++) lq[r] = __shfl(l, lc * 4 + r);
#pragma unroll
        for (int r = 0; r < 4; r++) {
            float inv = 1.f / lq[r];
            int qr = qrow0 + lc * 4 + r;
#pragma unroll
            for (int dt = 0; dt < 4; dt++)
                O[((size_t)(bb * S_ + qr)) * E_ + hh * HD + dt * 16 + lr] = f2bf(o[dt][r] * inv);
        }
    }
}

extern "C" void kernel_launch(void* const* d_in, const int* in_sizes, int n_in,
                              void* d_out, int out_size, void* d_ws, size_t ws_size,
                              hipStream_t stream) {
    const float* x      = (const float*)d_in[0];
    const float* w_attn = (const float*)d_in[1];
    const float* b_attn = (const float*)d_in[2];
    const float* w_proj = (const float*)d_in[3];
    const float* b_proj = (const float*)d_in[4];
    float* out = (float*)d_out;

    char* ws = (char*)d_ws;
    const size_t M = (size_t)B_ * S_;             // 8192
    unsigned short* xb  = (unsigned short*)(ws);                         // 8192*768
    unsigned short* waT = (unsigned short*)(ws + 12582912);              // 2304*768
    unsigned short* wpT = (unsigned short*)(ws + 16121856);              // 768*768
    unsigned short* Qb  = (unsigned short*)(ws + 17301504);              // BH*S*D
    unsigned short* Kb  = (unsigned short*)(ws + 29884416);
    unsigned short* Vt  = (unsigned short*)(ws + 42467328);
    unsigned short* AO  = (unsigned short*)(ws + 55050240);              // 8192*768

    int n4 = (int)(M * E_ / 4);
    cvt_kernel<<<(n4 + 255) / 256, 256, 0, stream>>>(x, xb, n4);
    transpose_cvt<<<dim3(3 * E_ / 32, E_ / 32), dim3(32, 32), 0, stream>>>(w_attn, waT, E_, 3 * E_);
    transpose_cvt<<<dim3(E_ / 32, E_ / 32), dim3(32, 32), 0, stream>>>(w_proj, wpT, E_, E_);

    gemm16<0><<<2304, 256, 0, stream>>>(
        xb, waT, b_attn, Qb, Kb, Vt, nullptr, (int)M, 3 * E_, E_);

    attn_kernel<<<1536, 256, 0, stream>>>(Qb, Kb, Vt, AO);

    gemm16<1><<<768, 256, 0, stream>>>(
        AO, wpT, b_proj, nullptr, nullptr, nullptr, out, (int)M, E_, E_);
}

// Round 25
// 136.968 us; speedup vs baseline: 1.2211x; 1.0338x over previous
//
#include <hip/hip_runtime.h>
#include <hip/hip_bf16.h>

typedef __attribute__((ext_vector_type(8))) __bf16 bf16x8;
typedef __attribute__((ext_vector_type(4))) __bf16 bf16x4;
typedef __attribute__((ext_vector_type(4))) float f32x4;

#define E_ 768
#define HEADS 12
#define HD 64
#define S_ 2048
#define B_ 4

__device__ inline unsigned short f2bf(float f) {
    union { float f; unsigned int u; } x{f};
    unsigned int r = x.u + 0x7FFFu + ((x.u >> 16) & 1u);
    return (unsigned short)(r >> 16);
}

__device__ inline float fexp2(float x) { return __builtin_amdgcn_exp2f(x); }

// ---------- merged prologue: x cvt + both weight transposes ----------
// grid 8448 x 256: [0,6144) cvt fp32->bf16 of x; [6144,7872) w_attn 32x32
// transpose tiles; [7872,8448) w_proj tiles. Same math as the separate
// kernels (tile[32][33] padding kept; 4 row-passes per 256-thread block).
__global__ __launch_bounds__(256) void prep_kernel(
    const float* __restrict__ x, unsigned short* __restrict__ xb, int n4,
    const float* __restrict__ wa, unsigned short* __restrict__ waT,
    const float* __restrict__ wp, unsigned short* __restrict__ wpT)
{
    const int g = blockIdx.x;
    const int t = threadIdx.x;
    if (g < 6144) {
        int i = g * 256 + t;
        if (i < n4) {
            float4 v = reinterpret_cast<const float4*>(x)[i];
            ushort4 o;
            o.x = f2bf(v.x); o.y = f2bf(v.y); o.z = f2bf(v.z); o.w = f2bf(v.w);
            reinterpret_cast<ushort4*>(xb)[i] = o;
        }
        return;
    }
    __shared__ float tile[32][33];
    const float* w; unsigned short* wT; int K, N, idx;
    if (g < 6144 + 1728) { w = wa; wT = waT; K = E_; N = 3 * E_; idx = g - 6144; }
    else                 { w = wp; wT = wpT; K = E_; N = E_;     idx = g - 7872; }
    const int nbx = N >> 5;
    const int n0 = (idx % nbx) * 32, k0 = (idx / nbx) * 32;
    const int tx = t & 31, ty0 = t >> 5;          // 32 x 8
#pragma unroll
    for (int r = 0; r < 4; r++) {
        const int row = ty0 + r * 8;
        tile[row][tx] = w[(size_t)(k0 + row) * N + n0 + tx];
    }
    __syncthreads();
#pragma unroll
    for (int r = 0; r < 4; r++) {
        const int row = ty0 + r * 8;              // output row offset (n)
        wT[(size_t)(n0 + row) * K + k0 + tx] = f2bf(tile[tx][row]);
    }
}

// ---------- bf16 MFMA GEMM, BN=64, T3-min DOUBLE-BUFFERED K-loop ----------
// (unchanged from R24, verified)
template<int MODE>
__global__ __launch_bounds__(256) void gemm16(
    const unsigned short* __restrict__ A, const unsigned short* __restrict__ Bt,
    const float* __restrict__ bias,
    unsigned short* __restrict__ Qo, unsigned short* __restrict__ Ko,
    unsigned short* __restrict__ Vt, float* __restrict__ Of,
    int M, int N, int K)
{
    constexpr int BN = 64;
    constexpr int NJ = 2;
    __shared__ unsigned short Sh[2][128 * 64 + 64 * 64];   // 2 x 24 KB = 48 KB
    unsigned short* Shf = &Sh[0][0];

    const int nbx = N / BN;
    const int nwg = (M >> 7) * nbx;
    const int cpx = nwg >> 3;
    const int orig = blockIdx.x;
    const int wgid = (orig & 7) * cpx + (orig >> 3);   // XCD-chunked (nwg%8==0)
    const int row0 = (wgid / nbx) * 128;
    const int col0 = (wgid % nbx) * BN;

    const int t = threadIdx.x;
    const int w = t >> 6, lane = t & 63;
    const int lr = lane & 15, lc = lane >> 4;
    const int wrow = (w >> 1) * 64;
    const int wcol = (w & 1) * 32;

    const int srow = lane >> 3;
    const int sslot = lane & 7;

    f32x4 acc[4][NJ] = {};

    auto stage = [&](int buf, int k0) {
        unsigned short* Ad = &Sh[buf][0];
        unsigned short* Bd = &Sh[buf][128 * 64];
#pragma unroll
        for (int j = 0; j < 4; j++) {
            const int rbase = j * 32 + w * 8;
            const unsigned short* ga = A + (size_t)(row0 + rbase + srow) * K + k0 + sslot * 8;
            __builtin_amdgcn_global_load_lds(
                (const __attribute__((address_space(1))) void*)ga,
                (__attribute__((address_space(3))) void*)&Ad[rbase * 64], 16, 0, 0);
        }
#pragma unroll
        for (int j = 0; j < NJ; j++) {
            const int rbase = j * 32 + w * 8;
            const unsigned short* gb = Bt + (size_t)(col0 + rbase + srow) * K + k0 + sslot * 8;
            __builtin_amdgcn_global_load_lds(
                (const __attribute__((address_space(1))) void*)gb,
                (__attribute__((address_space(3))) void*)&Bd[rbase * 64], 16, 0, 0);
        }
    };

    stage(0, 0);
    asm volatile("s_waitcnt vmcnt(0)" ::: "memory");
    __syncthreads();

    int cur = 0;
    for (int k0 = 0; k0 < K; k0 += 64) {
        if (k0 + 64 < K) stage(cur ^ 1, k0 + 64);   // issue next tile EARLY

        const unsigned short* Ac = &Sh[cur][0];
        const unsigned short* Bc = &Sh[cur][128 * 64];
#pragma unroll
        for (int ks = 0; ks < 2; ks++) {
            bf16x8 a[4], b[NJ];
#pragma unroll
            for (int i = 0; i < 4; i++)
                a[i] = *reinterpret_cast<const bf16x8*>(&Ac[(wrow + i * 16 + lr) * 64 + ks * 32 + lc * 8]);
#pragma unroll
            for (int j2 = 0; j2 < NJ; j2++)
                b[j2] = *reinterpret_cast<const bf16x8*>(&Bc[(wcol + j2 * 16 + lr) * 64 + ks * 32 + lc * 8]);
#pragma unroll
            for (int i = 0; i < 4; i++)
#pragma unroll
                for (int j2 = 0; j2 < NJ; j2++)
                    acc[i][j2] = __builtin_amdgcn_mfma_f32_16x16x32_bf16(a[i], b[j2], acc[i][j2], 0, 0, 0);
        }
        asm volatile("s_waitcnt vmcnt(0)" ::: "memory");
        __syncthreads();
        cur ^= 1;
    }

    if constexpr (MODE == 0) {
        const int bb = row0 >> 11;
        const int s0 = row0 & (S_ - 1);
        const int which = col0 / E_;                   // 0=Q, 1=K, 2=V (uniform per block)
        const int h = (col0 - which * E_) >> 6;        // single head per block
        const size_t bh = (size_t)(bb * HEADS + h);
        if (which == 2) {
#pragma unroll
            for (int i = 0; i < 4; i++)
#pragma unroll
                for (int j = 0; j < NJ; j++) {
                    const int c = wcol + j * 16 + lr;
                    const float bv = bias[col0 + c];
#pragma unroll
                    for (int r = 0; r < 4; r++) {
                        const int row = wrow + i * 16 + lc * 4 + r;
                        Shf[c * 128 + (row ^ ((c & 15) << 3))] = f2bf(acc[i][j][r] + bv);
                    }
                }
            __syncthreads();
#pragma unroll
            for (int pass = 0; pass < 4; pass++) {
                const int c = pass * 16 + (t >> 4);
                const int sL = (t & 15) * 8;
                bf16x8 vv = *reinterpret_cast<const bf16x8*>(&Shf[c * 128 + (sL ^ ((c & 15) << 3))]);
                *reinterpret_cast<bf16x8*>(&Vt[(bh * HD + c) * S_ + s0 + sL]) = vv;
            }
            return;
        }
        const float qsc = (which == 0) ? 0.18033688f : 1.0f;   // 0.125*log2e into Q
        unsigned short* dst = (which == 0) ? Qo : Ko;
#pragma unroll
        for (int i = 0; i < 4; i++)
#pragma unroll
            for (int j = 0; j < NJ; j++) {
                const int c = wcol + j * 16 + lr;
                const float bv = bias[col0 + c];
#pragma unroll
                for (int r = 0; r < 4; r++) {
                    const int row = wrow + i * 16 + lc * 4 + r;
                    Shf[row * 64 + (c ^ ((row & 7) << 3))] = f2bf((acc[i][j][r] + bv) * qsc);
                }
            }
        __syncthreads();
#pragma unroll
        for (int pass = 0; pass < 4; pass++) {
            const int row = pass * 32 + (t >> 3);
            const int c2 = (t & 7) * 8;
            bf16x8 vv = *reinterpret_cast<const bf16x8*>(&Shf[row * 64 + (c2 ^ ((row & 7) << 3))]);
            *reinterpret_cast<bf16x8*>(&dst[(bh * S_ + s0 + row) * HD + c2]) = vv;
        }
    } else {
#pragma unroll
        for (int i = 0; i < 4; i++)
#pragma unroll
            for (int j = 0; j < NJ; j++) {
                int col = col0 + wcol + j * 16 + lr;
                float bv = bias[col];
#pragma unroll
                for (int r = 0; r < 4; r++) {
                    int row = row0 + wrow + i * 16 + lc * 4 + r;
                    Of[(size_t)row * N + col] = acc[i][j][r] + bv;
                }
            }
    }
}

// ---------- causal flash attention, one q-tile per block (R23/R24, verified) ----------
__global__ __launch_bounds__(256) void attn_kernel(
    const unsigned short* __restrict__ Q, const unsigned short* __restrict__ Kd,
    const unsigned short* __restrict__ Vt, unsigned short* __restrict__ O)
{
    __shared__ unsigned short Ksh[128 * 64];
    __shared__ unsigned short Vsh[64 * 128];

    const int t = threadIdx.x;
    const int w = t >> 6, lane = t & 63;
    const int lr = lane & 15, lc = lane >> 4;
    const int g = blockIdx.x;
    const int tile = 31 - g / 48;          // largest tiles dispatch first
    const int bh = g % 48;
    const int qrow0 = tile * 64 + w * 16;
    const int nIter = (tile + 2) >> 1;

    const unsigned short* Qb = Q + (size_t)bh * S_ * HD;
    const unsigned short* Kb = Kd + (size_t)bh * S_ * HD;
    const unsigned short* Vb = Vt + (size_t)bh * HD * S_;

    const int srK = t >> 3, ssK = t & 7;
    const int kws = ((ssK ^ (srK & 7)) << 3);
    const int srV = t >> 4, ssV = t & 15;
    const int vs1 = (ssV >> 2) * 4 + (ssV & 1) * 2;
    const int voff = ((ssV >> 1) & 1) * 4;
    const int vws1 = ((vs1 ^ srV) << 3) + voff;
    const int vws2 = (((vs1 + 1) ^ srV) << 3) + voff;
    const int r7 = lr & 7;

    const unsigned short* KbS = Kb + (size_t)srK * HD + ssK * 8;
    const unsigned short* VbS = Vb + (size_t)srV * S_ + ssV * 8;

    bf16x8 aq0, aq1;
    aq0 = *reinterpret_cast<const bf16x8*>(Qb + (size_t)(qrow0 + lr) * HD + lc * 8);
    aq1 = *reinterpret_cast<const bf16x8*>(Qb + (size_t)(qrow0 + lr) * HD + 32 + lc * 8);

    f32x4 o[4] = {};
    float m = -INFINITY, l = 0.f;
    const int bb = bh / HEADS, hh = bh - bb * HEADS;
    const int qrow = qrow0 + lr;

    bf16x8 kreg[4], vreg[4];
#pragma unroll
    for (int i = 0; i < 4; i++) {
        kreg[i] = *reinterpret_cast<const bf16x8*>(KbS + i * 32 * HD);
        vreg[i] = *reinterpret_cast<const bf16x8*>(VbS + i * 16 * S_);
    }

    for (int it = 0; it < nIter; ++it) {
        __syncthreads();
#pragma unroll
        for (int i = 0; i < 4; i++) {
            *reinterpret_cast<bf16x8*>(&Ksh[(srK + i * 32) * 64 + kws]) = kreg[i];
            union { bf16x8 v; bf16x4 h[2]; } u2;
            u2.v = vreg[i];
            const int vrow = (srV + i * 16) * 128;
            *reinterpret_cast<bf16x4*>(&Vsh[vrow + vws1]) = u2.h[0];
            *reinterpret_cast<bf16x4*>(&Vsh[vrow + vws2]) = u2.h[1];
        }
        __syncthreads();

        if (it + 1 < nIter) {
            const int nkv0 = (it + 1) * 128;
#pragma unroll
            for (int i = 0; i < 4; i++) {
                kreg[i] = *reinterpret_cast<const bf16x8*>(KbS + (size_t)nkv0 * HD + i * 32 * HD);
                vreg[i] = *reinterpret_cast<const bf16x8*>(VbS + nkv0 + i * 16 * S_);
            }
        }

        const int kv0 = it * 128;
        const bool needMask = (it == nIter - 1);

        float p[8][4];
#pragma unroll
        for (int kt = 0; kt < 8; kt++) {
            const int row = kt * 16 + lr;
            const bf16x8 bk0 = *reinterpret_cast<const bf16x8*>(&Ksh[row * 64 + ((lc ^ r7) << 3)]);
            const bf16x8 bk1 = *reinterpret_cast<const bf16x8*>(&Ksh[row * 64 + (((4 + lc) ^ r7) << 3)]);
            f32x4 s = {};
            s = __builtin_amdgcn_mfma_f32_16x16x32_bf16(bk0, aq0, s, 0, 0, 0);
            s = __builtin_amdgcn_mfma_f32_16x16x32_bf16(bk1, aq1, s, 0, 0, 0);
#pragma unroll
            for (int r = 0; r < 4; r++) p[kt][r] = s[r];
        }
        if (needMask) {
#pragma unroll
            for (int kt = 0; kt < 8; kt++) {
                const int kbase = kv0 + kt * 16 + lc * 4;
#pragma unroll
                for (int r = 0; r < 4; r++)
                    if (kbase + r > qrow) p[kt][r] = -1e30f;
            }
        }

        float rm = -1e30f;
#pragma unroll
        for (int kt = 0; kt < 8; kt++)
#pragma unroll
            for (int r = 0; r < 4; r++) rm = fmaxf(rm, p[kt][r]);
        rm = fmaxf(rm, __shfl_xor(rm, 16));
        rm = fmaxf(rm, __shfl_xor(rm, 32));

        const bool grow = !__all(rm <= m);
        float mn = m, sc;
        if (grow) {
            mn = fmaxf(m, rm);
            sc = fexp2(m - mn);
        }

        float rs = 0.f;
#pragma unroll
        for (int kt = 0; kt < 8; kt++)
#pragma unroll
            for (int r = 0; r < 4; r++) {
                float e = fexp2(p[kt][r] - mn);
                p[kt][r] = e; rs += e;
            }
        rs += __shfl_xor(rs, 16);
        rs += __shfl_xor(rs, 32);

        if (grow) {
            l = l * sc + rs;
            m = mn;
            float scq[4];
#pragma unroll
            for (int r = 0; r < 4; r++) scq[r] = __shfl(sc, lc * 4 + r);
#pragma unroll
            for (int dt = 0; dt < 4; dt++)
#pragma unroll
                for (int r = 0; r < 4; r++) o[dt][r] *= scq[r];
        } else {
            l += rs;
        }

        bf16x8 ap[4];
#pragma unroll
        for (int kc = 0; kc < 4; kc++) {
            union { bf16x8 v; __bf16 b[8]; } u2;
            u2.b[0] = (__bf16)p[2 * kc][0];     u2.b[1] = (__bf16)p[2 * kc][1];
            u2.b[2] = (__bf16)p[2 * kc][2];     u2.b[3] = (__bf16)p[2 * kc][3];
            u2.b[4] = (__bf16)p[2 * kc + 1][0]; u2.b[5] = (__bf16)p[2 * kc + 1][1];
            u2.b[6] = (__bf16)p[2 * kc + 1][2]; u2.b[7] = (__bf16)p[2 * kc + 1][3];
            ap[kc] = u2.v;
        }

#pragma unroll
        for (int dt = 0; dt < 4; dt++) {
            const int row = dt * 16 + lr;
#pragma unroll
            for (int kc = 0; kc < 4; kc++) {
                const bf16x8 bv = *reinterpret_cast<const bf16x8*>(
                    &Vsh[row * 128 + (((kc * 4 + lc) ^ lr) << 3)]);
                o[dt] = __builtin_amdgcn_mfma_f32_16x16x32_bf16(ap[kc], bv, o[dt], 0, 0, 0);
            }
        }
    }

    {
        float lq[4];
#pragma unroll
        for (int r = 0; r < 4; r++) lq[r] = __shfl(l, lc * 4 + r);
#pragma unroll
        for (int r = 0; r < 4; r++) {
            float inv = 1.f / lq[r];
            int qr = qrow0 + lc * 4 + r;
#pragma unroll
            for (int dt = 0; dt < 4; dt++)
                O[((size_t)(bb * S_ + qr)) * E_ + hh * HD + dt * 16 + lr] = f2bf(o[dt][r] * inv);
        }
    }
}

extern "C" void kernel_launch(void* const* d_in, const int* in_sizes, int n_in,
                              void* d_out, int out_size, void* d_ws, size_t ws_size,
                              hipStream_t stream) {
    const float* x      = (const float*)d_in[0];
    const float* w_attn = (const float*)d_in[1];
    const float* b_attn = (const float*)d_in[2];
    const float* w_proj = (const float*)d_in[3];
    const float* b_proj = (const float*)d_in[4];
    float* out = (float*)d_out;

    char* ws = (char*)d_ws;
    const size_t M = (size_t)B_ * S_;             // 8192
    unsigned short* xb  = (unsigned short*)(ws);                         // 8192*768
    unsigned short* waT = (unsigned short*)(ws + 12582912);              // 2304*768
    unsigned short* wpT = (unsigned short*)(ws + 16121856);              // 768*768
    unsigned short* Qb  = (unsigned short*)(ws + 17301504);              // BH*S*D
    unsigned short* Kb  = (unsigned short*)(ws + 29884416);
    unsigned short* Vt  = (unsigned short*)(ws + 42467328);
    unsigned short* AO  = (unsigned short*)(ws + 55050240);              // 8192*768

    int n4 = (int)(M * E_ / 4);
    prep_kernel<<<8448, 256, 0, stream>>>(x, xb, n4, w_attn, waT, w_proj, wpT);

    gemm16<0><<<2304, 256, 0, stream>>>(
        xb, waT, b_attn, Qb, Kb, Vt, nullptr, (int)M, 3 * E_, E_);

    attn_kernel<<<1536, 256, 0, stream>>>(Qb, Kb, Vt, AO);

    gemm16<1><<<768, 256, 0, stream>>>(
        AO, wpT, b_proj, nullptr, nullptr, nullptr, out, (int)M, E_, E_);
}